// Round 2
// baseline (49871.094 us; speedup 1.0000x reference)
//
#include <hip/hip_runtime.h>

// shallowPLRNN on MI355X — round 2: robustness rewrite.
// - No cooperative launch, no hipFuncSetAttribute, static LDS <= 64KB everywhere.
// - Workspace need: 2.38 MB (forcing lives in d_out, fp32).
// - 16 subject-groups x 8 blocks; weights resident in VGPR MFMA fragments;
//   per-step exchange of z (fp32) and hidden (f16) via global + spin barriers.

typedef _Float16 f16;
typedef _Float16 f16x8 __attribute__((ext_vector_type(8)));
typedef float f32x4 __attribute__((ext_vector_type(4)));

#define TSTEPS 1024

// ---- workspace byte offsets (total 2378880 bytes ~= 2.27 MB) ----
#define WS_C     0ul          // C table: 64x64 fp32
#define WS_ZG    16384ul      // z state: 16 subj x 48 x 256 fp32
#define WS_HIDG  802816ul     // hidden exchange: 16 subj x 48 x 1024 f16
#define WS_ORDER 2375680ul    // sample order (256 int)
#define WS_CNT   2376704ul    // per-subject count (16 int)
#define WS_OFFS  2376768ul    // per-subject offset (16 int)
#define WS_CTR   2376832ul    // barrier counters (16 x 128B)
#define WS_NEED  2378880ul

// ---- main-kernel static LDS layout (bytes, total 54208) ----
#define SM_ZPK   0            // zpk:  [48][280] f16 (post-TF z)  — aliased by red[]
#define SM_ZPRE  26880        // zpre: [48][72]  f16 (pre-TF z, k<64, for decode)
#define SM_ZSL   33792        // zsl:  [48][32]  fp32 (block's z slice, post-TF)
#define SM_TBUF  39936        // tbuf: [48][144] f16 (hidden transpose buffer)
#define SM_AH    53760        // ah:   A[32], h1[32] fp32
#define SM_ORD   54016        // ordl: [48] int
#define SM_SIZE  54208

__device__ __forceinline__ unsigned pack2f16(float x, float y) {
    union { f16 h[2]; unsigned u; } v;
    v.h[0] = (f16)x; v.h[1] = (f16)y;
    return v.u;
}

// 8-block per-subject barrier; monotonic counter. All threads fence (release
// before signal, acquire after) so both compiler and HW ordering hold for
// every thread's surrounding global accesses, agent scope (cross-XCD safe).
__device__ __forceinline__ void group_barrier(int* ctr, int target) {
    __threadfence();   // release: every thread's prior stores -> agent scope
    __syncthreads();   // all fences done before the signal
    if (threadIdx.x == 0) {
        __hip_atomic_fetch_add(ctr, 1, __ATOMIC_RELEASE, __HIP_MEMORY_SCOPE_AGENT);
        while (__hip_atomic_load(ctr, __ATOMIC_ACQUIRE, __HIP_MEMORY_SCOPE_AGENT) < target)
            __builtin_amdgcn_s_sleep(2);
    }
    __syncthreads();   // signal observed before anyone proceeds
    __threadfence();   // acquire: invalidate stale cached lines for all threads
}

// ---------- prep: C = (M^T M)^-1 M[:64,:]^T  (64x64), fp32 Gauss-Jordan ----------
// G = M^T M is strongly diagonally dominant (cond ~ 9) -> no pivoting, fp32 ok.
__global__ __launch_bounds__(256) void prep_kernel(const float* __restrict__ M,
                                                   float* __restrict__ C) {
    __shared__ float aug[64 * 132];   // [64][132]: cols 0..63 = G, 64..127 = M[:64,:]^T
    __shared__ float fac[64];
    int tid = threadIdx.x;
    {   // G[i][j0..j0+15]
        int i = tid >> 2;
        int j0 = (tid & 3) * 16;
        float acc[16];
        #pragma unroll
        for (int e = 0; e < 16; ++e) acc[e] = 0.f;
        for (int r = 0; r < 256; ++r) {
            float mi = M[r*64 + i];
            #pragma unroll
            for (int e = 0; e < 16; ++e) acc[e] += mi * M[r*64 + j0 + e];
        }
        #pragma unroll
        for (int e = 0; e < 16; ++e) aug[i*132 + j0 + e] = acc[e];
    }
    for (int idx = tid; idx < 4096; idx += 256) {  // N[x][c] = M[c][x]
        int x = idx >> 6, c = idx & 63;
        aug[x*132 + 64 + c] = M[c*64 + x];
    }
    __syncthreads();
    for (int p = 0; p < 64; ++p) {
        float piv = aug[p*132 + p];
        __syncthreads();
        if (tid < 128) aug[p*132 + tid] /= piv;
        __syncthreads();
        if (tid < 64) fac[tid] = aug[tid*132 + p];
        __syncthreads();
        for (int idx = tid; idx < 8192; idx += 256) {
            int r = idx >> 7, c = idx & 127;
            if (r != p) aug[r*132 + c] -= fac[r] * aug[p*132 + c];
        }
        __syncthreads();
    }
    for (int idx = tid; idx < 4096; idx += 256) {
        int x = idx >> 6, c = idx & 63;
        C[x*64 + c] = aug[x*132 + 64 + c];
    }
}

// ---------- forcing: out[b][t][0:64] = x[b][t][:] @ C   (fp32, into d_out!) ----------
// d_out doubles as the forcing buffer; decode at iter t+1 overwrites out[b][t]
// strictly after the last read of forcing[b][t] (iter t), separated by barriers.
__global__ __launch_bounds__(256) void forcing_kernel(const float* __restrict__ x,
        const float* __restrict__ C, float* __restrict__ fout) {
    __shared__ float xs[64 * 68];
    __shared__ float Cs[64 * 64];
    int tid = threadIdx.x;
    for (int i = tid; i < 1024; i += 256)
        ((float4*)Cs)[i] = ((const float4*)C)[i];
    long r0 = (long)blockIdx.x * 64;       // 64 consecutive (b,t) rows, same b
    int b  = (int)(r0 >> 10);
    int t0 = (int)(r0 & 1023);
    const float4* xb = (const float4*)(x + ((long)b * 1024 + t0) * 64);
    for (int i = tid; i < 1024; i += 256) {
        float4 v = xb[i];
        int row = i >> 4, col = (i & 15) * 4;
        *(float4*)&xs[row*68 + col] = v;
    }
    __syncthreads();
    int row = tid >> 2, cg = (tid & 3) * 16;
    float acc[16];
    #pragma unroll
    for (int e = 0; e < 16; ++e) acc[e] = 0.f;
    for (int k = 0; k < 64; ++k) {
        float xv = xs[row*68 + k];
        const float* cr = &Cs[k*64 + cg];
        #pragma unroll
        for (int e = 0; e < 16; ++e) acc[e] += xv * cr[e];
    }
    float4* dst = (float4*)(fout + ((size_t)b*1024 + t0 + row)*64 + cg);
    #pragma unroll
    for (int e = 0; e < 4; ++e) {
        float4 v; v.x = acc[4*e]; v.y = acc[4*e+1]; v.z = acc[4*e+2]; v.w = acc[4*e+3];
        dst[e] = v;
    }
}

// ---------- grouping: bucket samples by subject, zero barrier counters ----------
__global__ __launch_bounds__(256) void group_kernel(const int* __restrict__ subject,
        int* order, int* cnt, int* offs, int* ctr) {
    __shared__ int lc[16], lo[16], cur[16];
    int tid = threadIdx.x;
    if (tid < 16) { lc[tid] = 0; cur[tid] = 0; }
    __syncthreads();
    int s = subject[tid];
    atomicAdd(&lc[s], 1);
    __syncthreads();
    if (tid == 0) { int a = 0; for (int i = 0; i < 16; ++i) { lo[i] = a; a += lc[i]; } }
    __syncthreads();
    int pos = lo[s] + atomicAdd(&cur[s], 1);
    order[pos] = tid;
    if (tid < 16) { cnt[tid] = lc[tid]; offs[tid] = lo[tid]; ctr[tid*32] = 0; }
}

// ---------- main persistent kernel (regular launch, 128 blocks <= 256 CUs) ----------
template<int NT>
__device__ __forceinline__ void run_group(int s, int j, int Bs, int off,
    const float* __restrict__ W1t, const float* __restrict__ W2t,
    const float* __restrict__ At,  const float* __restrict__ h1t,
    const float* __restrict__ h2t, const float* __restrict__ Mt,
    float* __restrict__ zg, f16* __restrict__ hidg,
    const int* __restrict__ order, int* ctr, float* out, char* sm)
{
    f16*   zpk   = (f16*)(sm + SM_ZPK);      // [48][280] f16, post-TF z
    f16*   zpre  = (f16*)(sm + SM_ZPRE);     // [48][72] f16, pre-TF z (k<64)
    float* zsl   = (float*)(sm + SM_ZSL);    // [48][32] fp32 post-TF slice
    f16*   tbuf  = (f16*)(sm + SM_TBUF);     // [48][144] f16 hidden transpose buf
    float* ah    = (float*)(sm + SM_AH);     // A[32], h1[32]
    int*   ordl  = (int*)(sm + SM_ORD);      // [48]
    float* red   = (float*)(sm + SM_ZPK);    // phase-B reduction, aliases zpk (24.6KB<26.9KB)

    const int tid  = threadIdx.x;
    const int w    = tid >> 6;
    const int lane = tid & 63;
    const int q    = lane >> 4;
    const int li   = lane & 15;

    float* zgs = zg + (size_t)s * (48*256);
    char*  hgs = (char*)hidg + (size_t)s * (48*1024*2);

    if (tid < 48) ordl[tid] = (tid < Bs) ? order[off + tid] : 0;
    if (tid >= 64 && tid < 96)  ah[tid-64]      = At [s*256 + 32*j + (tid-64)];
    if (tid >= 96 && tid < 128) ah[tid-96+32]   = h1t[s*256 + 32*j + (tid-96)];
    __syncthreads();

    // ---- preload weight fragments into VGPRs (held across all T steps) ----
    f16x8 w2f[2][8], w1f[2][8], mfr[8];
    float h2v[2][4];
    const f32x4 zero4 = {0.f, 0.f, 0.f, 0.f};
    #pragma unroll
    for (int m = 0; m < 2; ++m) {   // W2 rows [128j..128j+128): A-frag
        const float* src = W2t + (size_t)s*262144 + (size_t)(128*j + (2*w+m)*16 + li)*256;
        #pragma unroll
        for (int kt = 0; kt < 8; ++kt) {
            int k0 = kt*32 + q*8;
            #pragma unroll
            for (int e = 0; e < 8; ++e) w2f[m][kt][e] = (f16)src[k0+e];
        }
    }
    #pragma unroll
    for (int m = 0; m < 2; ++m) {   // W1 rows [32j..32j+32); wave w owns k-chunk 256w..
        const float* src = W1t + (size_t)s*262144 + (size_t)(32*j + m*16 + li)*1024;
        #pragma unroll
        for (int kt = 0; kt < 8; ++kt) {
            int k0 = (8*w + kt)*32 + q*8;
            #pragma unroll
            for (int e = 0; e < 8; ++e) w1f[m][kt][e] = (f16)src[k0+e];
        }
    }
    #pragma unroll
    for (int kt = 0; kt < 8; ++kt)   // obs_matrix B-frags; wave w owns dx cols [16w,16w+16)
        #pragma unroll
        for (int e = 0; e < 8; ++e)
            mfr[kt][e] = (f16)Mt[(kt*32 + q*8 + e)*64 + 16*w + li];
    #pragma unroll
    for (int m = 0; m < 2; ++m)
        #pragma unroll
        for (int r = 0; r < 4; ++r)
            h2v[m][r] = h2t[s*1024 + 128*j + (2*w+m)*16 + q*4 + r];

    // ---- init z0: dims<64 = forcing[:,0,:64] (read from out), else 0 ----
    for (int idx = tid; idx < NT*512; idx += 256) {
        int n = idx >> 5, zdl = idx & 31;
        int zd = 32*j + zdl;
        float v = 0.f;
        if (zd < 64 && n < Bs) v = out[(size_t)ordl[n]*65536 + zd];
        zgs[n*256 + zd] = v;
    }
    int gen = 1;
    group_barrier(ctr, 8*gen);

    for (int t = 0; t <= TSTEPS; ++t) {
        // ---- stage z: fp32 global -> f16 LDS (post-TF zpk, pre-TF zpre, fp32 zsl) ----
        {
            int half = tid >> 7;
            int kk = (tid & 127) * 2;
            int kl = kk - 32*j;
            #pragma unroll
            for (int i = 0; i < NT*8; ++i) {
                int n = i*2 + half;
                float zx = 0.f, zy = 0.f;
                if (n < Bs) {
                    float2 zz = *(const float2*)&zgs[n*256 + kk];
                    zx = zz.x; zy = zz.y;
                }
                float px = zx, py = zy;
                if (kk < 64) {
                    ((unsigned*)zpre)[n*36 + (kk>>1)] = pack2f16(zx, zy);
                    if (t < TSTEPS && n < Bs) {
                        float2 fv = *(const float2*)&out[((size_t)ordl[n]*1024 + t)*64 + kk];
                        px = 0.2f*fv.x + 0.8f*zx;
                        py = 0.2f*fv.y + 0.8f*zy;
                    }
                }
                ((unsigned*)zpk)[n*140 + (kk>>1)] = pack2f16(px, py);
                if (kl >= 0 && kl < 32) {
                    float2 pv; pv.x = px; pv.y = py;
                    *(float2*)&zsl[n*32 + kl] = pv;
                }
            }
        }
        __syncthreads();

        // ---- fused decode of previous state: out[b][t-1] = z_{t-1} @ M ----
        if (t > 0 && j < NT) {      // block j decodes sample tile j (no duplication)
            f32x4 dacc = zero4;
            #pragma unroll
            for (int kt = 0; kt < 8; ++kt) {
                f16x8 af;
                if (kt < 2) af = *(const f16x8*)&zpre[(16*j + li)*72 + kt*32 + q*8];
                else        af = *(const f16x8*)&zpk [(16*j + li)*280 + kt*32 + q*8];
                dacc = __builtin_amdgcn_mfma_f32_16x16x32_f16(af, mfr[kt], dacc, 0, 0, 0);
            }
            #pragma unroll
            for (int r = 0; r < 4; ++r) {
                int n = 16*j + q*4 + r;
                if (n < Bs)
                    out[((size_t)ordl[n]*TSTEPS + (t-1))*64 + 16*w + li] = dacc[r];
            }
        }
        if (t == TSTEPS) break;

        // ---- phase A: hidden slice [128j..128j+128) = relu(W2*z + h2) ----
        {
            f32x4 acc[2][NT];
            #pragma unroll
            for (int m = 0; m < 2; ++m)
                #pragma unroll
                for (int nt = 0; nt < NT; ++nt) acc[m][nt] = zero4;
            #pragma unroll
            for (int nt = 0; nt < NT; ++nt) {
                #pragma unroll
                for (int kt = 0; kt < 8; ++kt) {
                    f16x8 bf = *(const f16x8*)&zpk[(16*nt + li)*280 + kt*32 + q*8];
                    acc[0][nt] = __builtin_amdgcn_mfma_f32_16x16x32_f16(w2f[0][kt], bf, acc[0][nt], 0,0,0);
                    acc[1][nt] = __builtin_amdgcn_mfma_f32_16x16x32_f16(w2f[1][kt], bf, acc[1][nt], 0,0,0);
                }
            }
            #pragma unroll
            for (int m = 0; m < 2; ++m)
                #pragma unroll
                for (int nt = 0; nt < NT; ++nt)
                    #pragma unroll
                    for (int r = 0; r < 4; ++r) {
                        float hv = acc[m][nt][r] + h2v[m][r];
                        hv = hv > 0.f ? hv : 0.f;
                        tbuf[(nt*16 + li)*144 + (2*w+m)*16 + q*4 + r] = (f16)hv;
                    }
        }
        __syncthreads();
        for (int c = tid; c < NT*256; c += 256) {   // store transposed slice to hidg
            int n = c >> 4, cc = c & 15;
            *(f16x8*)(hgs + n*2048 + j*256 + cc*16) = *(const f16x8*)&tbuf[n*144 + cc*8];
        }
        ++gen; group_barrier(ctr, 8*gen);

        // ---- phase B: z slice [32j..32j+32) = A*z + W1*hidden + h1 ----
        // hidden B-frags loaded straight from global hidg (16B/lane, L2-hot)
        {
            f32x4 bacc[2][NT];
            #pragma unroll
            for (int m = 0; m < 2; ++m)
                #pragma unroll
                for (int nt = 0; nt < NT; ++nt) bacc[m][nt] = zero4;
            #pragma unroll
            for (int nt = 0; nt < NT; ++nt) {
                #pragma unroll
                for (int kt = 0; kt < 8; ++kt) {
                    f16x8 bf = *(const f16x8*)(hgs + (16*nt + li)*2048 + (8*w + kt)*64 + q*16);
                    bacc[0][nt] = __builtin_amdgcn_mfma_f32_16x16x32_f16(w1f[0][kt], bf, bacc[0][nt], 0,0,0);
                    bacc[1][nt] = __builtin_amdgcn_mfma_f32_16x16x32_f16(w1f[1][kt], bf, bacc[1][nt], 0,0,0);
                }
            }
            __syncthreads();   // zpk B-frag reads (phase A) done before red[] overwrite
            #pragma unroll
            for (int m = 0; m < 2; ++m)
                #pragma unroll
                for (int nt = 0; nt < NT; ++nt)
                    *(f32x4*)&red[(size_t)((w*6 + m*3 + nt)*256 + lane*4)] = bacc[m][nt];
        }
        __syncthreads();
        for (int idx = tid; idx < NT*512; idx += 256) {   // cross-wave reduce + A*z + h1
            int zdl = idx & 31, n = idx >> 5;
            int m = zdl >> 4, qq = (zdl >> 2) & 3, r = zdl & 3;
            int ln = qq*16 + (n & 15), nt = n >> 4;
            float sum = 0.f;
            #pragma unroll
            for (int ww = 0; ww < 4; ++ww)
                sum += red[(ww*6 + m*3 + nt)*256 + ln*4 + r];
            float zv = ah[zdl] * zsl[n*32 + zdl] + sum + ah[32 + zdl];
            if (n < Bs) zgs[n*256 + 32*j + zdl] = zv;
        }
        ++gen; group_barrier(ctr, 8*gen);
    }
}

__global__ __launch_bounds__(256, 1) void main_kernel(
    const float* W1t, const float* W2t, const float* At, const float* h1t,
    const float* h2t, const float* Mt, float* zg, f16* hidg,
    const int* order, const int* cnt, const int* offs, int* ctr, float* out)
{
    __shared__ __align__(16) char sm[SM_SIZE];
    int bid = blockIdx.x;
    int s = (bid & 7) + 8*(bid >> 6);   // group's 8 blocks share bid%8 (XCD affinity)
    int j = (bid >> 3) & 7;
    int Bs = cnt[s];
    if (Bs <= 0) return;                 // whole group exits consistently
    if (Bs > 48) Bs = 48;
    int off = offs[s];
    int* myctr = ctr + s*32;
    int NT = (Bs + 15) >> 4;
    if (NT == 1)
        run_group<1>(s, j, Bs, off, W1t, W2t, At, h1t, h2t, Mt, zg, hidg, order, myctr, out, sm);
    else if (NT == 2)
        run_group<2>(s, j, Bs, off, W1t, W2t, At, h1t, h2t, Mt, zg, hidg, order, myctr, out, sm);
    else
        run_group<3>(s, j, Bs, off, W1t, W2t, At, h1t, h2t, Mt, zg, hidg, order, myctr, out, sm);
}

extern "C" void kernel_launch(void* const* d_in, const int* in_sizes, int n_in,
                              void* d_out, int out_size, void* d_ws, size_t ws_size,
                              hipStream_t stream) {
    const float* x    = (const float*)d_in[0];
    const int*   subj = (const int*)d_in[1];
    const float* Mt   = (const float*)d_in[2];
    const float* At   = (const float*)d_in[3];
    const float* W1t  = (const float*)d_in[4];
    const float* W2t  = (const float*)d_in[5];
    const float* h1t  = (const float*)d_in[6];
    const float* h2t  = (const float*)d_in[7];
    float* out = (float*)d_out;
    char*  ws  = (char*)d_ws;
    if (ws_size < WS_NEED) return;  // fail-soft (need only 2.38 MB now)

    float* C     = (float*)(ws + WS_C);
    float* zg    = (float*)(ws + WS_ZG);
    f16*   hidg  = (f16*)(ws + WS_HIDG);
    int*   order = (int*)(ws + WS_ORDER);
    int*   cnt   = (int*)(ws + WS_CNT);
    int*   offs  = (int*)(ws + WS_OFFS);
    int*   ctr   = (int*)(ws + WS_CTR);

    prep_kernel<<<1, 256, 0, stream>>>(Mt, C);
    forcing_kernel<<<4096, 256, 0, stream>>>(x, C, out);
    group_kernel<<<1, 256, 0, stream>>>(subj, order, cnt, offs, ctr);
    main_kernel<<<128, 256, 0, stream>>>(W1t, W2t, At, h1t, h2t, Mt,
                                         zg, hidg, order, cnt, offs, ctr, out);
}

// Round 3
// 15129.306 us; speedup vs baseline: 3.2963x; 3.2963x over previous
//
#include <hip/hip_runtime.h>

// shallowPLRNN on MI355X — round 3: barrier de-fencing.
// Identical compute structure to the passing round-2 kernel; only the
// group_barrier changed: relaxed polls + single thread-0 release/acquire
// fences (2 cache-maintenance ops per barrier instead of ~16+N).

typedef _Float16 f16;
typedef _Float16 f16x8 __attribute__((ext_vector_type(8)));
typedef float f32x4 __attribute__((ext_vector_type(4)));

#define TSTEPS 1024

// ---- workspace byte offsets (total 2378880 bytes ~= 2.27 MB) ----
#define WS_C     0ul          // C table: 64x64 fp32
#define WS_ZG    16384ul      // z state: 16 subj x 48 x 256 fp32
#define WS_HIDG  802816ul     // hidden exchange: 16 subj x 48 x 1024 f16
#define WS_ORDER 2375680ul    // sample order (256 int)
#define WS_CNT   2376704ul    // per-subject count (16 int)
#define WS_OFFS  2376768ul    // per-subject offset (16 int)
#define WS_CTR   2376832ul    // barrier counters (16 x 128B)
#define WS_NEED  2378880ul

// ---- main-kernel static LDS layout (bytes, total 54208) ----
#define SM_ZPK   0            // zpk:  [48][280] f16 (post-TF z)  — aliased by red[]
#define SM_ZPRE  26880        // zpre: [48][72]  f16 (pre-TF z, k<64, for decode)
#define SM_ZSL   33792        // zsl:  [48][32]  fp32 (block's z slice, post-TF)
#define SM_TBUF  39936        // tbuf: [48][144] f16 (hidden transpose buffer)
#define SM_AH    53760        // ah:   A[32], h1[32] fp32
#define SM_ORD   54016        // ordl: [48] int
#define SM_SIZE  54208

__device__ __forceinline__ unsigned pack2f16(float x, float y) {
    union { f16 h[2]; unsigned u; } v;
    v.h[0] = (f16)x; v.h[1] = (f16)y;
    return v.u;
}

// 8-block per-subject barrier; monotonic counter, agent scope.
// HW reasoning: __syncthreads() drains each wave's vmcnt (stores have reached
// the XCD L2 through the write-through L1), so thread 0's release fence
// (buffer_wbl2 sc1) flushes ALL waves' data to the coherence point; after the
// relaxed poll succeeds, thread 0's acquire fence (buffer_inv sc1) invalidates
// the CU-shared L1 + XCD L2 for all 4 waves of the block. The surrounding
// __syncthreads() provide compiler + execution ordering for the other waves.
__device__ __forceinline__ void group_barrier(int* ctr, int target) {
    __syncthreads();
    if (threadIdx.x == 0) {
        __builtin_amdgcn_fence(__ATOMIC_RELEASE, "agent");   // buffer_wbl2 sc1
        __hip_atomic_fetch_add(ctr, 1, __ATOMIC_RELAXED, __HIP_MEMORY_SCOPE_AGENT);
        while (__hip_atomic_load(ctr, __ATOMIC_RELAXED, __HIP_MEMORY_SCOPE_AGENT) < target)
            __builtin_amdgcn_s_sleep(1);
        __builtin_amdgcn_fence(__ATOMIC_ACQUIRE, "agent");   // buffer_inv sc1
    }
    __syncthreads();
}

// ---------- prep: C = (M^T M)^-1 M[:64,:]^T  (64x64), fp32 Gauss-Jordan ----------
// G = M^T M is strongly diagonally dominant (cond ~ 9) -> no pivoting, fp32 ok.
__global__ __launch_bounds__(256) void prep_kernel(const float* __restrict__ M,
                                                   float* __restrict__ C) {
    __shared__ float aug[64 * 132];   // [64][132]: cols 0..63 = G, 64..127 = M[:64,:]^T
    __shared__ float fac[64];
    int tid = threadIdx.x;
    {   // G[i][j0..j0+15]
        int i = tid >> 2;
        int j0 = (tid & 3) * 16;
        float acc[16];
        #pragma unroll
        for (int e = 0; e < 16; ++e) acc[e] = 0.f;
        for (int r = 0; r < 256; ++r) {
            float mi = M[r*64 + i];
            #pragma unroll
            for (int e = 0; e < 16; ++e) acc[e] += mi * M[r*64 + j0 + e];
        }
        #pragma unroll
        for (int e = 0; e < 16; ++e) aug[i*132 + j0 + e] = acc[e];
    }
    for (int idx = tid; idx < 4096; idx += 256) {  // N[x][c] = M[c][x]
        int x = idx >> 6, c = idx & 63;
        aug[x*132 + 64 + c] = M[c*64 + x];
    }
    __syncthreads();
    for (int p = 0; p < 64; ++p) {
        float piv = aug[p*132 + p];
        __syncthreads();
        if (tid < 128) aug[p*132 + tid] /= piv;
        __syncthreads();
        if (tid < 64) fac[tid] = aug[tid*132 + p];
        __syncthreads();
        for (int idx = tid; idx < 8192; idx += 256) {
            int r = idx >> 7, c = idx & 127;
            if (r != p) aug[r*132 + c] -= fac[r] * aug[p*132 + c];
        }
        __syncthreads();
    }
    for (int idx = tid; idx < 4096; idx += 256) {
        int x = idx >> 6, c = idx & 63;
        C[x*64 + c] = aug[x*132 + 64 + c];
    }
}

// ---------- forcing: out[b][t][0:64] = x[b][t][:] @ C   (fp32, into d_out!) ----------
// d_out doubles as the forcing buffer; decode at iter t+1 overwrites out[b][t]
// strictly after the last read of forcing[b][t] (iter t), separated by barriers.
__global__ __launch_bounds__(256) void forcing_kernel(const float* __restrict__ x,
        const float* __restrict__ C, float* __restrict__ fout) {
    __shared__ float xs[64 * 68];
    __shared__ float Cs[64 * 64];
    int tid = threadIdx.x;
    for (int i = tid; i < 1024; i += 256)
        ((float4*)Cs)[i] = ((const float4*)C)[i];
    long r0 = (long)blockIdx.x * 64;       // 64 consecutive (b,t) rows, same b
    int b  = (int)(r0 >> 10);
    int t0 = (int)(r0 & 1023);
    const float4* xb = (const float4*)(x + ((long)b * 1024 + t0) * 64);
    for (int i = tid; i < 1024; i += 256) {
        float4 v = xb[i];
        int row = i >> 4, col = (i & 15) * 4;
        *(float4*)&xs[row*68 + col] = v;
    }
    __syncthreads();
    int row = tid >> 2, cg = (tid & 3) * 16;
    float acc[16];
    #pragma unroll
    for (int e = 0; e < 16; ++e) acc[e] = 0.f;
    for (int k = 0; k < 64; ++k) {
        float xv = xs[row*68 + k];
        const float* cr = &Cs[k*64 + cg];
        #pragma unroll
        for (int e = 0; e < 16; ++e) acc[e] += xv * cr[e];
    }
    float4* dst = (float4*)(fout + ((size_t)b*1024 + t0 + row)*64 + cg);
    #pragma unroll
    for (int e = 0; e < 4; ++e) {
        float4 v; v.x = acc[4*e]; v.y = acc[4*e+1]; v.z = acc[4*e+2]; v.w = acc[4*e+3];
        dst[e] = v;
    }
}

// ---------- grouping: bucket samples by subject, zero barrier counters ----------
__global__ __launch_bounds__(256) void group_kernel(const int* __restrict__ subject,
        int* order, int* cnt, int* offs, int* ctr) {
    __shared__ int lc[16], lo[16], cur[16];
    int tid = threadIdx.x;
    if (tid < 16) { lc[tid] = 0; cur[tid] = 0; }
    __syncthreads();
    int s = subject[tid];
    atomicAdd(&lc[s], 1);
    __syncthreads();
    if (tid == 0) { int a = 0; for (int i = 0; i < 16; ++i) { lo[i] = a; a += lc[i]; } }
    __syncthreads();
    int pos = lo[s] + atomicAdd(&cur[s], 1);
    order[pos] = tid;
    if (tid < 16) { cnt[tid] = lc[tid]; offs[tid] = lo[tid]; ctr[tid*32] = 0; }
}

// ---------- main persistent kernel (regular launch, 128 blocks <= 256 CUs) ----------
template<int NT>
__device__ __forceinline__ void run_group(int s, int j, int Bs, int off,
    const float* __restrict__ W1t, const float* __restrict__ W2t,
    const float* __restrict__ At,  const float* __restrict__ h1t,
    const float* __restrict__ h2t, const float* __restrict__ Mt,
    float* __restrict__ zg, f16* __restrict__ hidg,
    const int* __restrict__ order, int* ctr, float* out, char* sm)
{
    f16*   zpk   = (f16*)(sm + SM_ZPK);      // [48][280] f16, post-TF z
    f16*   zpre  = (f16*)(sm + SM_ZPRE);     // [48][72] f16, pre-TF z (k<64)
    float* zsl   = (float*)(sm + SM_ZSL);    // [48][32] fp32 post-TF slice
    f16*   tbuf  = (f16*)(sm + SM_TBUF);     // [48][144] f16 hidden transpose buf
    float* ah    = (float*)(sm + SM_AH);     // A[32], h1[32]
    int*   ordl  = (int*)(sm + SM_ORD);      // [48]
    float* red   = (float*)(sm + SM_ZPK);    // phase-B reduction, aliases zpk (24.6KB<26.9KB)

    const int tid  = threadIdx.x;
    const int w    = tid >> 6;
    const int lane = tid & 63;
    const int q    = lane >> 4;
    const int li   = lane & 15;

    float* zgs = zg + (size_t)s * (48*256);
    char*  hgs = (char*)hidg + (size_t)s * (48*1024*2);

    if (tid < 48) ordl[tid] = (tid < Bs) ? order[off + tid] : 0;
    if (tid >= 64 && tid < 96)  ah[tid-64]      = At [s*256 + 32*j + (tid-64)];
    if (tid >= 96 && tid < 128) ah[tid-96+32]   = h1t[s*256 + 32*j + (tid-96)];
    __syncthreads();

    // ---- preload weight fragments into VGPRs (held across all T steps) ----
    f16x8 w2f[2][8], w1f[2][8], mfr[8];
    float h2v[2][4];
    const f32x4 zero4 = {0.f, 0.f, 0.f, 0.f};
    #pragma unroll
    for (int m = 0; m < 2; ++m) {   // W2 rows [128j..128j+128): A-frag
        const float* src = W2t + (size_t)s*262144 + (size_t)(128*j + (2*w+m)*16 + li)*256;
        #pragma unroll
        for (int kt = 0; kt < 8; ++kt) {
            int k0 = kt*32 + q*8;
            #pragma unroll
            for (int e = 0; e < 8; ++e) w2f[m][kt][e] = (f16)src[k0+e];
        }
    }
    #pragma unroll
    for (int m = 0; m < 2; ++m) {   // W1 rows [32j..32j+32); wave w owns k-chunk 256w..
        const float* src = W1t + (size_t)s*262144 + (size_t)(32*j + m*16 + li)*1024;
        #pragma unroll
        for (int kt = 0; kt < 8; ++kt) {
            int k0 = (8*w + kt)*32 + q*8;
            #pragma unroll
            for (int e = 0; e < 8; ++e) w1f[m][kt][e] = (f16)src[k0+e];
        }
    }
    #pragma unroll
    for (int kt = 0; kt < 8; ++kt)   // obs_matrix B-frags; wave w owns dx cols [16w,16w+16)
        #pragma unroll
        for (int e = 0; e < 8; ++e)
            mfr[kt][e] = (f16)Mt[(kt*32 + q*8 + e)*64 + 16*w + li];
    #pragma unroll
    for (int m = 0; m < 2; ++m)
        #pragma unroll
        for (int r = 0; r < 4; ++r)
            h2v[m][r] = h2t[s*1024 + 128*j + (2*w+m)*16 + q*4 + r];

    // ---- init z0: dims<64 = forcing[:,0,:64] (read from out), else 0 ----
    for (int idx = tid; idx < NT*512; idx += 256) {
        int n = idx >> 5, zdl = idx & 31;
        int zd = 32*j + zdl;
        float v = 0.f;
        if (zd < 64 && n < Bs) v = out[(size_t)ordl[n]*65536 + zd];
        zgs[n*256 + zd] = v;
    }
    int gen = 1;
    group_barrier(ctr, 8*gen);

    for (int t = 0; t <= TSTEPS; ++t) {
        // ---- stage z: fp32 global -> f16 LDS (post-TF zpk, pre-TF zpre, fp32 zsl) ----
        {
            int half = tid >> 7;
            int kk = (tid & 127) * 2;
            int kl = kk - 32*j;
            #pragma unroll
            for (int i = 0; i < NT*8; ++i) {
                int n = i*2 + half;
                float zx = 0.f, zy = 0.f;
                if (n < Bs) {
                    float2 zz = *(const float2*)&zgs[n*256 + kk];
                    zx = zz.x; zy = zz.y;
                }
                float px = zx, py = zy;
                if (kk < 64) {
                    ((unsigned*)zpre)[n*36 + (kk>>1)] = pack2f16(zx, zy);
                    if (t < TSTEPS && n < Bs) {
                        float2 fv = *(const float2*)&out[((size_t)ordl[n]*1024 + t)*64 + kk];
                        px = 0.2f*fv.x + 0.8f*zx;
                        py = 0.2f*fv.y + 0.8f*zy;
                    }
                }
                ((unsigned*)zpk)[n*140 + (kk>>1)] = pack2f16(px, py);
                if (kl >= 0 && kl < 32) {
                    float2 pv; pv.x = px; pv.y = py;
                    *(float2*)&zsl[n*32 + kl] = pv;
                }
            }
        }
        __syncthreads();

        // ---- fused decode of previous state: out[b][t-1] = z_{t-1} @ M ----
        if (t > 0 && j < NT) {      // block j decodes sample tile j (no duplication)
            f32x4 dacc = zero4;
            #pragma unroll
            for (int kt = 0; kt < 8; ++kt) {
                f16x8 af;
                if (kt < 2) af = *(const f16x8*)&zpre[(16*j + li)*72 + kt*32 + q*8];
                else        af = *(const f16x8*)&zpk [(16*j + li)*280 + kt*32 + q*8];
                dacc = __builtin_amdgcn_mfma_f32_16x16x32_f16(af, mfr[kt], dacc, 0, 0, 0);
            }
            #pragma unroll
            for (int r = 0; r < 4; ++r) {
                int n = 16*j + q*4 + r;
                if (n < Bs)
                    out[((size_t)ordl[n]*TSTEPS + (t-1))*64 + 16*w + li] = dacc[r];
            }
        }
        if (t == TSTEPS) break;

        // ---- phase A: hidden slice [128j..128j+128) = relu(W2*z + h2) ----
        {
            f32x4 acc[2][NT];
            #pragma unroll
            for (int m = 0; m < 2; ++m)
                #pragma unroll
                for (int nt = 0; nt < NT; ++nt) acc[m][nt] = zero4;
            #pragma unroll
            for (int nt = 0; nt < NT; ++nt) {
                #pragma unroll
                for (int kt = 0; kt < 8; ++kt) {
                    f16x8 bf = *(const f16x8*)&zpk[(16*nt + li)*280 + kt*32 + q*8];
                    acc[0][nt] = __builtin_amdgcn_mfma_f32_16x16x32_f16(w2f[0][kt], bf, acc[0][nt], 0,0,0);
                    acc[1][nt] = __builtin_amdgcn_mfma_f32_16x16x32_f16(w2f[1][kt], bf, acc[1][nt], 0,0,0);
                }
            }
            #pragma unroll
            for (int m = 0; m < 2; ++m)
                #pragma unroll
                for (int nt = 0; nt < NT; ++nt)
                    #pragma unroll
                    for (int r = 0; r < 4; ++r) {
                        float hv = acc[m][nt][r] + h2v[m][r];
                        hv = hv > 0.f ? hv : 0.f;
                        tbuf[(nt*16 + li)*144 + (2*w+m)*16 + q*4 + r] = (f16)hv;
                    }
        }
        __syncthreads();
        for (int c = tid; c < NT*256; c += 256) {   // store transposed slice to hidg
            int n = c >> 4, cc = c & 15;
            *(f16x8*)(hgs + n*2048 + j*256 + cc*16) = *(const f16x8*)&tbuf[n*144 + cc*8];
        }
        ++gen; group_barrier(ctr, 8*gen);

        // ---- phase B: z slice [32j..32j+32) = A*z + W1*hidden + h1 ----
        // hidden B-frags loaded straight from global hidg (16B/lane, L2-hot)
        {
            f32x4 bacc[2][NT];
            #pragma unroll
            for (int m = 0; m < 2; ++m)
                #pragma unroll
                for (int nt = 0; nt < NT; ++nt) bacc[m][nt] = zero4;
            #pragma unroll
            for (int nt = 0; nt < NT; ++nt) {
                #pragma unroll
                for (int kt = 0; kt < 8; ++kt) {
                    f16x8 bf = *(const f16x8*)(hgs + (16*nt + li)*2048 + (8*w + kt)*64 + q*16);
                    bacc[0][nt] = __builtin_amdgcn_mfma_f32_16x16x32_f16(w1f[0][kt], bf, bacc[0][nt], 0,0,0);
                    bacc[1][nt] = __builtin_amdgcn_mfma_f32_16x16x32_f16(w1f[1][kt], bf, bacc[1][nt], 0,0,0);
                }
            }
            __syncthreads();   // zpk/zpre last reads done before red[] overwrite
            #pragma unroll
            for (int m = 0; m < 2; ++m)
                #pragma unroll
                for (int nt = 0; nt < NT; ++nt)
                    *(f32x4*)&red[(size_t)((w*6 + m*3 + nt)*256 + lane*4)] = bacc[m][nt];
        }
        __syncthreads();
        for (int idx = tid; idx < NT*512; idx += 256) {   // cross-wave reduce + A*z + h1
            int zdl = idx & 31, n = idx >> 5;
            int m = zdl >> 4, qq = (zdl >> 2) & 3, r = zdl & 3;
            int ln = qq*16 + (n & 15), nt = n >> 4;
            float sum = 0.f;
            #pragma unroll
            for (int ww = 0; ww < 4; ++ww)
                sum += red[(ww*6 + m*3 + nt)*256 + ln*4 + r];
            float zv = ah[zdl] * zsl[n*32 + zdl] + sum + ah[32 + zdl];
            if (n < Bs) zgs[n*256 + 32*j + zdl] = zv;
        }
        ++gen; group_barrier(ctr, 8*gen);
    }
}

__global__ __launch_bounds__(256, 1) void main_kernel(
    const float* W1t, const float* W2t, const float* At, const float* h1t,
    const float* h2t, const float* Mt, float* zg, f16* hidg,
    const int* order, const int* cnt, const int* offs, int* ctr, float* out)
{
    __shared__ __align__(16) char sm[SM_SIZE];
    int bid = blockIdx.x;
    int s = (bid & 7) + 8*(bid >> 6);   // group's 8 blocks share bid%8 (XCD affinity)
    int j = (bid >> 3) & 7;
    int Bs = cnt[s];
    if (Bs <= 0) return;                 // whole group exits consistently
    if (Bs > 48) Bs = 48;
    int off = offs[s];
    int* myctr = ctr + s*32;
    int NT = (Bs + 15) >> 4;
    if (NT == 1)
        run_group<1>(s, j, Bs, off, W1t, W2t, At, h1t, h2t, Mt, zg, hidg, order, myctr, out, sm);
    else if (NT == 2)
        run_group<2>(s, j, Bs, off, W1t, W2t, At, h1t, h2t, Mt, zg, hidg, order, myctr, out, sm);
    else
        run_group<3>(s, j, Bs, off, W1t, W2t, At, h1t, h2t, Mt, zg, hidg, order, myctr, out, sm);
}

extern "C" void kernel_launch(void* const* d_in, const int* in_sizes, int n_in,
                              void* d_out, int out_size, void* d_ws, size_t ws_size,
                              hipStream_t stream) {
    const float* x    = (const float*)d_in[0];
    const int*   subj = (const int*)d_in[1];
    const float* Mt   = (const float*)d_in[2];
    const float* At   = (const float*)d_in[3];
    const float* W1t  = (const float*)d_in[4];
    const float* W2t  = (const float*)d_in[5];
    const float* h1t  = (const float*)d_in[6];
    const float* h2t  = (const float*)d_in[7];
    float* out = (float*)d_out;
    char*  ws  = (char*)d_ws;
    if (ws_size < WS_NEED) return;  // fail-soft (need only 2.38 MB)

    float* C     = (float*)(ws + WS_C);
    float* zg    = (float*)(ws + WS_ZG);
    f16*   hidg  = (f16*)(ws + WS_HIDG);
    int*   order = (int*)(ws + WS_ORDER);
    int*   cnt   = (int*)(ws + WS_CNT);
    int*   offs  = (int*)(ws + WS_OFFS);
    int*   ctr   = (int*)(ws + WS_CTR);

    prep_kernel<<<1, 256, 0, stream>>>(Mt, C);
    forcing_kernel<<<4096, 256, 0, stream>>>(x, C, out);
    group_kernel<<<1, 256, 0, stream>>>(subj, order, cnt, offs, ctr);
    main_kernel<<<128, 256, 0, stream>>>(W1t, W2t, At, h1t, h2t, Mt,
                                         zg, hidg, order, cnt, offs, ctr, out);
}